// Round 1
// 266.379 us; speedup vs baseline: 1.2259x; 1.2259x over previous
//
#include <hip/hip_runtime.h>
#include <stdint.h>

#define N_NODES 50000
#define N_EDGES 1600000
#define IN_CH   128
#define OUT_CH  64
#define CAP     72            // per-node slot capacity; P(Poisson(32) >= 72) ~ 6e-18
#define NBUCKET 196           // bucket = dst >> 8  (49999>>8 = 195)
#define BCAP    10240         // per-bucket edge capacity incl. x4 pad slack (mean 9660)
#define MB      782           // merged blocks: ceil(50000/64)
#define EPB2    2047          // edges per merged block; 782*2047 = 1600754 >= E
#define BKCAP   32            // per-(block,bucket) LDS stage cap; mean 10.4, fallback safe
#define NODES_PAD (NBUCKET * 256)   // 50176
#define SENTINEL 0xFFFFFFFFu  // impossible packed edge: src<<16 with src<=49999

typedef float  f32x4  __attribute__((ext_vector_type(4)));
typedef __bf16 bf16x8 __attribute__((ext_vector_type(8)));
typedef unsigned short u16x8 __attribute__((ext_vector_type(8)));

// ---------- small helpers ----------
__device__ __forceinline__ unsigned int f2bf(float f) {
    unsigned int u = __float_as_uint(f);
    u += 0x7fffu + ((u >> 16) & 1u);   // round-to-nearest-even
    return u >> 16;
}
__device__ __forceinline__ float lrelu(float v, float s) { return v > 0.f ? v : s * v; }

// split fp32 into bf16 hi (bit-truncated) + bf16 lo (RNE of exact residual)
__device__ __forceinline__ void split2(float f, unsigned short& hi, unsigned short& lo) {
    unsigned int u = __float_as_uint(f);
    hi = (unsigned short)(u >> 16);
    float r = f - __uint_as_float(u & 0xffff0000u);   // exact in fp32
    lo = (unsigned short)f2bf(r);
}

#define POOL_SCALE 268435456.0f        // 2^28 fixed-point for packed alpha-sum
#define POOL_MASK  ((1ull << 40) - 1ull)

// ---------- K1 (merged): MFMA GEMM phase, then bin phase (sequential, LDS reused) ----------
__global__ __launch_bounds__(256, 1) void k_gemmbin(
    const float* __restrict__ x, const float* __restrict__ W,
    const float* __restrict__ att_src, const float* __restrict__ att_dst,
    unsigned short* __restrict__ H, float* __restrict__ a_s, float* __restrict__ a_d,
    const int* __restrict__ ei, int* __restrict__ gcur,
    unsigned int* __restrict__ binned)
{
    __shared__ __align__(16) unsigned char smem[64 * 264 * 2];  // 33792 B, overlaid
    float* sx = (float*)smem;                   // [64][132] fp32 x tile (132: 16B-aligned rows)

    const int tid  = threadIdx.x;
    const int lane = tid & 63;
    const int lr   = lane & 15;                 // 16-lane group position
    const int lg   = lane >> 4;                 // group 0..3
    const int wv   = __builtin_amdgcn_readfirstlane(tid >> 6);   // wave = layer
    const int row0 = blockIdx.x * 64;

    // ======== phase 1a: stage x tile (fp32, stride 132) ========
    for (int idx = tid; idx < 64 * 32; idx += 256) {
        int r = idx >> 5, c4 = idx & 31;
        int row = row0 + r;
        float4 v = make_float4(0.f, 0.f, 0.f, 0.f);
        if (row < N_NODES) v = ((const float4*)(x + (size_t)row * IN_CH))[c4];
        *(float4*)(sx + r * 132 + c4 * 4) = v;
    }
    __syncthreads();

    // ======== phase 1b: bf16x3 MFMA GEMM: 64 rows x 64 ch x K=128, wave=layer ========
    f32x4 acc[4][4];
#pragma unroll
    for (int m = 0; m < 4; ++m)
#pragma unroll
        for (int n = 0; n < 4; ++n) acc[m][n] = (f32x4){0.f, 0.f, 0.f, 0.f};

    const float* Wl = W + (size_t)wv * IN_CH * OUT_CH;   // wave-uniform layer base

#pragma unroll 1
    for (int ks = 0; ks < 4; ++ks) {                     // K-step of 32
        // A fragments (x rows): lane holds A[m*16+lr][k], k = ks*32 + lg*8 + j
        bf16x8 ahi[4], alo[4];
#pragma unroll
        for (int m = 0; m < 4; ++m) {
            const float* xr = sx + (m * 16 + lr) * 132 + ks * 32 + lg * 8;
            float4 xa = *(const float4*)xr;              // ds_read_b128, 16B aligned
            float4 xb = *(const float4*)(xr + 4);
            float xs[8] = {xa.x, xa.y, xa.z, xa.w, xb.x, xb.y, xb.z, xb.w};
            u16x8 h, l;
#pragma unroll
            for (int j = 0; j < 8; ++j) {
                unsigned short a, b; split2(xs[j], a, b); h[j] = a; l[j] = b;
            }
            ahi[m] = __builtin_bit_cast(bf16x8, h);
            alo[m] = __builtin_bit_cast(bf16x8, l);
        }
        // B fragments (W): lane holds B[k][n*16+lr], same k-mapping as A
#pragma unroll
        for (int n = 0; n < 4; ++n) {
            const float* wb = Wl + (size_t)(ks * 32 + lg * 8) * OUT_CH + n * 16 + lr;
            u16x8 h, l;
#pragma unroll
            for (int j = 0; j < 8; ++j) {
                unsigned short a, b; split2(wb[j * OUT_CH], a, b); h[j] = a; l[j] = b;
            }
            bf16x8 bhi = __builtin_bit_cast(bf16x8, h);
            bf16x8 blo = __builtin_bit_cast(bf16x8, l);
#pragma unroll
            for (int m = 0; m < 4; ++m) {
                acc[m][n] = __builtin_amdgcn_mfma_f32_16x16x32_bf16(ahi[m], bhi, acc[m][n], 0, 0, 0);
                acc[m][n] = __builtin_amdgcn_mfma_f32_16x16x32_bf16(alo[m], bhi, acc[m][n], 0, 0, 0);
                acc[m][n] = __builtin_amdgcn_mfma_f32_16x16x32_bf16(ahi[m], blo, acc[m][n], 0, 0, 0);
            }
        }
    }

    // ======== a_s / a_d epilogue: per-row dot over 64 ch (registers + shuffles) ========
    // C layout (m89-verified): lane holds rows m*16 + lg*4 + q, col n*16 + lr.
    float As_c[4], Ad_c[4];
#pragma unroll
    for (int n = 0; n < 4; ++n) {
        As_c[n] = att_src[wv * OUT_CH + n * 16 + lr];
        Ad_c[n] = att_dst[wv * OUT_CH + n * 16 + lr];
    }
    float ps[16], pd[16];
#pragma unroll
    for (int m = 0; m < 4; ++m)
#pragma unroll
        for (int q = 0; q < 4; ++q) {
            float s = 0.f, d = 0.f;
#pragma unroll
            for (int n = 0; n < 4; ++n) {
                s = fmaf(acc[m][n][q], As_c[n], s);
                d = fmaf(acc[m][n][q], Ad_c[n], d);
            }
            ps[m * 4 + q] = s; pd[m * 4 + q] = d;
        }
    // butterfly all-reduce across the 16-lane col group (lg constant for offsets <=8)
#pragma unroll
    for (int off = 1; off <= 8; off <<= 1) {
#pragma unroll
        for (int i = 0; i < 16; ++i) {
            ps[i] += __shfl_xor(ps[i], off);
            pd[i] += __shfl_xor(pd[i], off);
        }
    }
    // static select chain (rule #20: no runtime array index -> no scratch)
    float vs = ps[0], vd = pd[0];
#pragma unroll
    for (int i = 1; i < 16; ++i) {
        bool e = (lr == i);
        vs = e ? ps[i] : vs;
        vd = e ? pd[i] : vd;
    }
    {
        int rg = row0 + (lr >> 2) * 16 + lg * 4 + (lr & 3);   // (m,q) = (lr>>2, lr&3)
        if (rg < N_NODES) { a_s[rg * 4 + wv] = vs; a_d[rg * 4 + wv] = vd; }
    }

    __syncthreads();   // all waves done reading sx; safe to overlay with bf16 H tile
    unsigned short* shs = (unsigned short*)smem;   // [64][264] bf16 H tile
#pragma unroll
    for (int m = 0; m < 4; ++m)
#pragma unroll
        for (int n = 0; n < 4; ++n)
#pragma unroll
            for (int q = 0; q < 4; ++q)
                shs[(m * 16 + lg * 4 + q) * 264 + wv * 64 + n * 16 + lr] =
                    (unsigned short)f2bf(acc[m][n][q]);
    __syncthreads();

    for (int idx = tid; idx < 64 * 32; idx += 256) {
        int r = idx >> 5, c8 = idx & 31;
        int row2 = row0 + r;
        if (row2 < N_NODES) {
            const uint4* srcp = (const uint4*)(shs + r * 264);
            ((uint4*)(H + (size_t)row2 * 256))[c8] = srcp[c8];
        }
    }
    __syncthreads();

    // ======== phase 2: bin edges into dst-buckets (acc[] dead, LDS reused) ========
    int* lcnt = (int*)smem;                               // [196]
    unsigned int* stage = (unsigned int*)(smem + 1024);   // [BKCAP][256]
    const int start = blockIdx.x * EPB2;
    const int end = (start + EPB2 < N_EDGES) ? start + EPB2 : N_EDGES;

    // self-detect int64 vs int32: odd 32-bit words all zero iff int64
    int probe = ei[2 * (start + tid) + 1];
    const int is64 = (__ballot(probe != 0) == 0ull) ? 1 : 0;

    for (int i = tid; i < NBUCKET; i += 256) lcnt[i] = 0;
    __syncthreads();

    for (int e = start + tid; e < end; e += 256) {
        int s = is64 ? ei[2 * (long long)e] : ei[e];
        int d = is64 ? ei[2 * ((long long)N_EDGES + e)] : ei[N_EDGES + e];
        int bk = d >> 8;
        unsigned int pk = ((unsigned int)s << 16) | (unsigned int)d;
        int pos = atomicAdd(&lcnt[bk], 1);
        if (pos < BKCAP) {
            stage[pos * 256 + bk] = pk;
        } else {                                   // rare fallback keeps x4 alignment
            int gi = atomicAdd(&gcur[bk], 4);
            if (gi + 3 < BCAP) {
                unsigned int* q = binned + bk * BCAP + gi;
                q[0] = pk; q[1] = SENTINEL; q[2] = SENTINEL; q[3] = SENTINEL;
            }
        }
    }
    __syncthreads();

    // one thread per bucket: reserve x4-aligned space, flush as 16B stores
    if (tid < NBUCKET) {
        int c = lcnt[tid];
        if (c > BKCAP) c = BKCAP;
        int cpad = (c + 3) & ~3;
        if (cpad) {
            int base = atomicAdd(&gcur[tid], cpad);
            if (base + cpad <= BCAP) {
                uint4* dst = (uint4*)(binned + tid * BCAP + base);  // base%4==0
                for (int p = 0; p < c; p += 4) {
                    uint4 v;
                    v.x = stage[p * 256 + tid];
                    v.y = (p + 1 < c) ? stage[(p + 1) * 256 + tid] : SENTINEL;
                    v.z = (p + 2 < c) ? stage[(p + 2) * 256 + tid] : SENTINEL;
                    v.w = (p + 3 < c) ? stage[(p + 3) * 256 + tid] : SENTINEL;
                    dst[p >> 2] = v;
                }
            }
        }
    }
}

// ---------- K2: per-bucket placement in LDS, coalesced flush; zeroes pool ----------
__global__ __launch_bounds__(256) void k_bucket(
    const unsigned int* __restrict__ binned, const int* __restrict__ gcur,
    unsigned short* __restrict__ slot, int* __restrict__ cnt_dst,
    unsigned long long* __restrict__ pool)
{
    __shared__ unsigned short sl[256 * CAP];   // 36864 B slot tile (256 nodes)
    __shared__ int cnt[256];
    const int b = blockIdx.x;
    const int tid = threadIdx.x;
    cnt[tid] = 0;
    int pidx = b * 256 + tid;
    if (pidx < N_NODES) pool[pidx] = 0ull;     // replaces memset dispatch
    __syncthreads();

    int total = gcur[b];
    if (total > BCAP) total = BCAP;
    const unsigned int* src = binned + b * BCAP;
    for (int i = tid; i < total; i += 256) {
        unsigned int p = src[i];                 // coalesced
        if (p == SENTINEL) continue;             // alignment pad
        int local = p & 255;                     // d & 255 (bucket = d>>8)
        int pos = atomicAdd(&cnt[local], 1);     // LDS atomic — no fabric traffic
        if (pos < CAP) sl[local * CAP + pos] = (unsigned short)(p >> 16);
    }
    __syncthreads();

    uint4* g = (uint4*)(slot + (size_t)b * 256 * CAP);
    const uint4* l = (const uint4*)sl;
    for (int i = tid; i < 256 * CAP * 2 / 16; i += 256) g[i] = l[i];
    cnt_dst[b * 256 + tid] = cnt[tid];
}

// ---------- K3: gather — lane-parallel ew precompute into LDS, then MLP loop ----------
__global__ __launch_bounds__(256) void k_gather(
    const unsigned short* __restrict__ H, const unsigned short* __restrict__ slot,
    const int* __restrict__ cnt_dst,
    const float* __restrict__ a_s, const float* __restrict__ a_d,
    const float* __restrict__ bias, unsigned long long* __restrict__ pool,
    float* __restrict__ out)
{
    __shared__ __align__(16) float ewlds[4][CAP * 4];   // per-wave ew stash, 4608 B

    const int lane = threadIdx.x & 63;
    const int wv = __builtin_amdgcn_readfirstlane(threadIdx.x >> 6);
    const int node = blockIdx.x * 4 + wv;          // grid*4 == N_NODES exactly
    int deg = __builtin_amdgcn_readfirstlane(cnt_dst[node]);
    if (deg > CAP) deg = CAP;
    const int layer = lane >> 4;
    float* ewl = ewlds[wv];

    const float4* as4p = (const float4*)a_s;
    const unsigned short* s16 = slot + (size_t)node * CAP;
    const float4 ad4 = ((const float4*)a_d)[node];  // wave-uniform

    // ---- precompute: all <=72 edges' 4-layer exp-weights, lane-parallel ----
#pragma unroll
    for (int base = 0; base < CAP; base += 64) {
        int j = base + lane;
        if (j < deg) {
            int s = s16[j];                        // coalesced 2B/lane
            float4 as4 = as4p[s];                  // 16B/lane gather (L2-hot, 800KB tbl)
            float t0 = as4.x + ad4.x, t1 = as4.y + ad4.y;
            float t2 = as4.z + ad4.z, t3 = as4.w + ad4.w;
            float4 e4;
            e4.x = __expf(fmaxf(t0, 0.2f * t0));
            e4.y = __expf(fmaxf(t1, 0.2f * t1));
            e4.z = __expf(fmaxf(t2, 0.2f * t2));
            e4.w = __expf(fmaxf(t3, 0.2f * t3));
            *(float4*)(ewl + j * 4) = e4;          // wave-private: no barrier needed
        }
    }

    // ---- phase A: feature accumulation + sumExp (no exp, no select) ----
    float ax = 0.f, ay = 0.f, az = 0.f, aw = 0.f, sumExp = 0.f;
    const uint2* Hp = (const uint2*)H + lane;      // lane's 8B of each 512B row

    auto body = [&](unsigned int s, int j) {
        float ew = ewl[j * 4 + layer];             // ds_read_b32 broadcast
        uint2 hv = Hp[(size_t)s * 64];             // 512B/wave coalesced
        ax = fmaf(ew, __uint_as_float(hv.x << 16), ax);
        ay = fmaf(ew, __uint_as_float(hv.x & 0xffff0000u), ay);
        az = fmaf(ew, __uint_as_float(hv.y << 16), az);
        aw = fmaf(ew, __uint_as_float(hv.y & 0xffff0000u), aw);
        sumExp += ew;
    };

    const unsigned int* sp = (const unsigned int*)s16;
    const int npair = deg >> 1;
    int j2 = 0;
    for (; j2 + 8 <= npair; j2 += 8) {             // 16 edges in flight
        uint4 pa = *(const uint4*)(sp + j2);
        uint4 pb = *(const uint4*)(sp + j2 + 4);
        body(pa.x & 0xffffu, 2*j2+0); body(pa.x >> 16, 2*j2+1);
        body(pa.y & 0xffffu, 2*j2+2); body(pa.y >> 16, 2*j2+3);
        body(pa.z & 0xffffu, 2*j2+4); body(pa.z >> 16, 2*j2+5);
        body(pa.w & 0xffffu, 2*j2+6); body(pa.w >> 16, 2*j2+7);
        body(pb.x & 0xffffu, 2*j2+8); body(pb.x >> 16, 2*j2+9);
        body(pb.y & 0xffffu, 2*j2+10); body(pb.y >> 16, 2*j2+11);
        body(pb.z & 0xffffu, 2*j2+12); body(pb.z >> 16, 2*j2+13);
        body(pb.w & 0xffffu, 2*j2+14); body(pb.w >> 16, 2*j2+15);
    }
    for (; j2 + 4 <= npair; j2 += 4) {             // 8 edges
        uint4 p4 = *(const uint4*)(sp + j2);
        body(p4.x & 0xffffu, 2*j2+0); body(p4.x >> 16, 2*j2+1);
        body(p4.y & 0xffffu, 2*j2+2); body(p4.y >> 16, 2*j2+3);
        body(p4.z & 0xffffu, 2*j2+4); body(p4.z >> 16, 2*j2+5);
        body(p4.w & 0xffffu, 2*j2+6); body(p4.w >> 16, 2*j2+7);
    }
    for (; j2 < npair; ++j2) {
        unsigned int pr = sp[j2];
        body(pr & 0xffffu, 2*j2); body(pr >> 16, 2*j2+1);
    }
    if (deg & 1) body(sp[npair] & 0xffffu, deg - 1);

    float inv = 1.0f / (sumExp + 1e-16f);          // normalize once per node
    float4 b = ((const float4*)bias)[lane];
    float v0 = lrelu(fmaf(ax, inv, b.x), 0.01f);
    float v1 = lrelu(fmaf(ay, inv, b.y), 0.01f);
    float v2 = lrelu(fmaf(az, inv, b.z), 0.01f);
    float v3 = lrelu(fmaf(aw, inv, b.w), 0.01f);
    // sum the 4 layers: partners are lane ^ 16, lane ^ 32
    v0 += __shfl_xor(v0, 16); v0 += __shfl_xor(v0, 32);
    v1 += __shfl_xor(v1, 16); v1 += __shfl_xor(v1, 32);
    v2 += __shfl_xor(v2, 16); v2 += __shfl_xor(v2, 32);
    v3 += __shfl_xor(v3, 16); v3 += __shfl_xor(v3, 32);

    if (lane < 16) {
        ((float4*)(out + (size_t)node * 64))[lane] = make_float4(v0, v1, v2, v3);
    }

    // phase B: fused pooling — LDS ews, one packed u64 atomic per edge
    float i0 = 1.0f / (__shfl(sumExp,  0) + 1e-16f);
    float i1 = 1.0f / (__shfl(sumExp, 16) + 1e-16f);
    float i2 = 1.0f / (__shfl(sumExp, 32) + 1e-16f);
    float i3 = 1.0f / (__shfl(sumExp, 48) + 1e-16f);
    for (int jj = lane; jj < deg; jj += 64) {
        int s = s16[jj];                           // coalesced 2B/lane
        float4 e4 = *(const float4*)(ewl + jj * 4);   // ds_read_b128, stashed
        float tot = e4.x * i0 + e4.y * i1 + e4.z * i2 + e4.w * i3;
        unsigned long long enc = (1ull << 40) |
            (unsigned long long)(tot * POOL_SCALE + 0.5f);
        atomicAdd(pool + s, enc);
    }
}

// ---------- K4: node scores ----------
__global__ __launch_bounds__(256) void k_final(
    const unsigned long long* __restrict__ pool, const int* __restrict__ dirp,
    float* __restrict__ out)
{
    int i = blockIdx.x * 256 + threadIdx.x;
    if (i >= N_NODES) return;
    unsigned long long v = pool[i];
    unsigned int cnt = (unsigned int)(v >> 40);
    float val = (float)((double)(v & POOL_MASK) * (1.0 / (double)POOL_SCALE));
    int di = dirp[0];
    float dirf = (di >= -1000 && di <= 1000) ? (float)di : __int_as_float(di);
    float denom = (cnt > 1u) ? (float)cnt : 1.0f;
    out[(size_t)N_NODES * 64 + i] = dirf * val / denom;
}

// ---------- launch ----------
extern "C" void kernel_launch(void* const* d_in, const int* in_sizes, int n_in,
                              void* d_out, int out_size, void* d_ws, size_t ws_size,
                              hipStream_t stream)
{
    const float* x       = (const float*)d_in[0];
    const float* W       = (const float*)d_in[1];
    const float* att_src = (const float*)d_in[2];
    const float* att_dst = (const float*)d_in[3];
    const float* bias    = (const float*)d_in[4];
    const int*   ei      = (const int*)d_in[5];
    const int*   dirp    = (const int*)d_in[6];
    float* out = (float*)d_out;

    char* w = (char*)d_ws;
    size_t off = 0;
    auto alloc = [&](size_t bytes) -> void* {
        void* p = w + off;
        off = (off + bytes + 255) & ~(size_t)255;
        return p;
    };
    int* gcur = (int*)alloc((size_t)NBUCKET * sizeof(int));          // zeroed by memset
    unsigned long long* pool = (unsigned long long*)alloc((size_t)N_NODES * sizeof(unsigned long long)); // zeroed by k_bucket
    float* a_s = (float*)alloc((size_t)N_NODES * 4 * sizeof(float));
    float* a_d = (float*)alloc((size_t)N_NODES * 4 * sizeof(float));
    int* cnt_dst = (int*)alloc((size_t)NODES_PAD * sizeof(int));
    unsigned int* binned = (unsigned int*)alloc((size_t)NBUCKET * BCAP * sizeof(unsigned int));
    unsigned short* slot = (unsigned short*)alloc((size_t)NODES_PAD * CAP * sizeof(unsigned short));
    unsigned short* H = (unsigned short*)alloc((size_t)N_NODES * 256 * sizeof(unsigned short));
    (void)ws_size; (void)in_sizes; (void)n_in; (void)out_size;

    hipMemsetAsync(gcur, 0, NBUCKET * sizeof(int), stream);
    k_gemmbin<<<MB, 256, 0, stream>>>(x, W, att_src, att_dst, H, a_s, a_d, ei, gcur, binned);
    k_bucket<<<NBUCKET, 256, 0, stream>>>(binned, gcur, slot, cnt_dst, pool);
    k_gather<<<N_NODES / 4, 256, 0, stream>>>(H, slot, cnt_dst, a_s, a_d, bias, pool, out);
    k_final<<<(N_NODES + 255) / 256, 256, 0, stream>>>(pool, dirp, out);
}